// Round 5
// baseline (107.564 us; speedup 1.0000x reference)
//
#include <hip/hip_runtime.h>

// out[b,co,h,w] = sum_ci dq( conv3x3(x[b,ci], W[ci,co]) + b[ci,co] )
// Bit-exactness contract (verified R3 absmax==0, R4 absmax=1.4e-6):
//   conv = sequential fmaf over k=(kh*3+kw) ascending, seeded from 0;
//   bias added after as plain f32 add; t = y * (float)(15/9); rintf (half-even);
//   dequant+sum: fmaf(q, 0.6f, acc), ci ascending. v_pk_* ops are IEEE per
//   32-bit half -> packed version is bit-identical per pixel.

typedef float v2f __attribute__((ext_vector_type(2)));

constexpr int B_    = 8;
constexpr int CIN   = 16;
constexpr int COUT  = 32;
constexpr int H_    = 112;
constexpr int W_    = 112;
constexpr int TILE  = 16;            // 112 = 7*16
constexpr int HALO  = TILE + 2;      // 18
constexpr int LDSW  = 21;            // odd row stride: spreads banks for 8-row wave footprint
constexpr int COG   = 4;             // co per half-block (block covers 8 co)

__global__ __launch_bounds__(256, 6)   // 6 blocks/CU: 6*24.2KB = 145KB LDS, 24 waves
void conv_quant_sum_kernel(const float* __restrict__ x,
                           const float* __restrict__ w,
                           const float* __restrict__ bias,
                           float* __restrict__ out)
{
#pragma clang fp contract(off)
    const float QS = (float)(15.0 / 9.0);   // 1.66666663f
    const float DQ = 0.6f;                  // post-round dequant multiplier

    __shared__ float xs[CIN][HALO][LDSW];

    const int t    = threadIdx.x;
    const int tx   = t & 7;          // column-pair index: pixels 2tx, 2tx+1
    const int ty   = (t >> 3) & 15;  // row
    const int half = t >> 7;         // 0: waves 0-1, 1: waves 2-3 (wave-uniform)
    const int tile_x = blockIdx.x * TILE;
    const int tile_y = blockIdx.y * TILE;
    const int b    = blockIdx.z >> 2;
    const int cog  = (blockIdx.z & 3) * 8 + half * COG;

    // ---- stage x halo tile (18x18 per ci, zero-padded at borders) ----
    const float* xb = x + (size_t)b * CIN * H_ * W_;
    for (int idx = t; idx < CIN * HALO * HALO; idx += 256) {
        int ci  = idx / (HALO * HALO);
        int rem = idx - ci * (HALO * HALO);
        int r   = rem / HALO;
        int c   = rem - r * HALO;
        int gh  = tile_y + r - 1;
        int gw  = tile_x + c - 1;
        float v = 0.0f;
        if ((unsigned)gh < (unsigned)H_ && (unsigned)gw < (unsigned)W_)
            v = xb[ci * H_ * W_ + gh * W_ + gw];
        xs[ci][r][c] = v;
    }
    __syncthreads();

    v2f acc[COG];
#pragma unroll
    for (int co = 0; co < COG; ++co) acc[co] = v2f{0.0f, 0.0f};

    for (int ci = 0; ci < CIN; ++ci) {
        // 3 rows x 4 cols of x feed the two 3x3 windows
        float xr[3][4];
#pragma unroll
        for (int r = 0; r < 3; ++r)
#pragma unroll
            for (int c = 0; c < 4; ++c)
                xr[r][c] = xs[ci][ty + r][2 * tx + c];

        v2f xw[3][3];
#pragma unroll
        for (int r = 0; r < 3; ++r) {
            xw[r][0] = v2f{xr[r][0], xr[r][1]};
            xw[r][1] = v2f{xr[r][1], xr[r][2]};
            xw[r][2] = v2f{xr[r][2], xr[r][3]};
        }

        // wave-uniform weight/bias indices -> scalar loads
        const float* wc = w + (ci * COUT + cog) * 9;
        const float* bc = bias + ci * COUT + cog;
#pragma unroll
        for (int co = 0; co < COG; ++co) {
            v2f s = v2f{0.0f, 0.0f};             // conv seeded from 0
#pragma unroll
            for (int k = 0; k < 9; ++k) {
                float wv = wc[co * 9 + k];
                s = __builtin_elementwise_fma(xw[k / 3][k % 3], v2f{wv, wv}, s);
            }
            float bv = bc[co];
            v2f y  = s + v2f{bv, bv};            // bias: separate f32 add (pk_add)
            v2f tq = y * v2f{QS, QS};            // pk_mul
            v2f q;
            q.x = rintf(tq.x);                   // v_rndne_f32 (half-even)
            q.y = rintf(tq.y);
            acc[co] = __builtin_elementwise_fma(q, v2f{DQ, DQ}, acc[co]);
        }
    }

    // ---- store: 2 adjacent pixels -> 8B-aligned dwordx2 ----
    float* ob = out + ((size_t)b * COUT + cog) * H_ * W_;
    const int oh = tile_y + ty;
    const int ow = tile_x + 2 * tx;              // even -> 8B aligned
#pragma unroll
    for (int co = 0; co < COG; ++co)
        *reinterpret_cast<v2f*>(ob + co * H_ * W_ + oh * W_ + ow) = acc[co];
}

extern "C" void kernel_launch(void* const* d_in, const int* in_sizes, int n_in,
                              void* d_out, int out_size, void* d_ws, size_t ws_size,
                              hipStream_t stream)
{
    const float* x    = (const float*)d_in[0];
    const float* w    = (const float*)d_in[1];
    const float* bias = (const float*)d_in[2];
    float* out        = (float*)d_out;

    dim3 grid(W_ / TILE, H_ / TILE, B_ * 4);   // (7, 7, 32) = 1568 blocks
    dim3 block(256);
    conv_quant_sum_kernel<<<grid, block, 0, stream>>>(x, w, bias, out);
}

// Round 6
// 88.734 us; speedup vs baseline: 1.2122x; 1.2122x over previous
//
#include <hip/hip_runtime.h>

// out[b,co,h,w] = sum_ci dq( conv3x3(x[b,ci], W[ci,co]) + b[ci,co] )
// Bit-exactness contract (verified R3 absmax==0, R4 absmax=1.4e-6):
//   conv = sequential fmaf over k=(kh*3+kw) ascending, seeded from 0;
//   bias added after as plain f32 add; t = y * (float)(15/9); rintf (half-even);
//   dequant+sum: fmaf(q, 0.6f, acc), ci ascending.
// Structure (R6): 8x8 tile, halo 10x10, LDS stride 12 (uniform 2-way banks =
// free). Block = 256 = 4 waves; wave w computes co-group w*8..w*8+7 so ONE
// staging serves all 32 co. Wave id via readfirstlane -> weight/bias loads
// stay wave-uniform scalar s_loads (R5 regression: divergent-looking group
// index turned them into per-lane VMEM loads).

constexpr int B_    = 8;
constexpr int CIN   = 16;
constexpr int COUT  = 32;
constexpr int H_    = 112;
constexpr int W_    = 112;
constexpr int TILE  = 8;             // 112 = 14*8
constexpr int HALO  = TILE + 2;      // 10
constexpr int LDSW  = 12;            // stride 12: (r*12+c) mod 32 -> exact 2-way
constexpr int COG   = 8;             // co per wave

__global__ __launch_bounds__(256, 8)   // 8 blocks/CU: 8*7.7KB=61KB LDS, 32 waves
void conv_quant_sum_kernel(const float* __restrict__ x,
                           const float* __restrict__ w,
                           const float* __restrict__ bias,
                           float* __restrict__ out)
{
#pragma clang fp contract(off)
    const float QS = (float)(15.0 / 9.0);   // 1.66666663f
    const float DQ = 0.6f;                  // post-round dequant multiplier

    __shared__ float xs[CIN][HALO][LDSW];   // 16*10*12*4 = 7.68 KB

    const int t   = threadIdx.x;
    const int tx  = t & 7;                  // col in 8x8 tile
    const int ty  = (t >> 3) & 7;           // row in 8x8 tile
    // wave id: genuinely wave-uniform; readfirstlane forces SGPR so the
    // compiler scalarizes every weight/bias access derived from it.
    const int wid = __builtin_amdgcn_readfirstlane(t >> 6);
    const int cog = wid * COG;

    const int tile_x = blockIdx.x * TILE;
    const int tile_y = blockIdx.y * TILE;
    const int b      = blockIdx.z;

    // ---- stage x halo tile (10x10 per ci, zero-padded at borders) ----
    const float* xb = x + (size_t)b * CIN * H_ * W_;
    for (int idx = t; idx < CIN * HALO * HALO; idx += 256) {
        int ci  = idx / (HALO * HALO);
        int rem = idx - ci * (HALO * HALO);
        int r   = rem / HALO;
        int c   = rem - r * HALO;
        int gh  = tile_y + r - 1;
        int gw  = tile_x + c - 1;
        float v = 0.0f;
        if ((unsigned)gh < (unsigned)H_ && (unsigned)gw < (unsigned)W_)
            v = xb[ci * H_ * W_ + gh * W_ + gw];
        xs[ci][r][c] = v;
    }
    __syncthreads();

    float acc[COG];
#pragma unroll
    for (int co = 0; co < COG; ++co) acc[co] = 0.0f;

    for (int ci = 0; ci < CIN; ++ci) {
        float xv[9];
#pragma unroll
        for (int r = 0; r < 3; ++r)
#pragma unroll
            for (int c = 0; c < 3; ++c)
                xv[r * 3 + c] = xs[ci][ty + r][tx + c];

        // wave-uniform (via wid) -> scalar s_load, zero VALU/VMEM-lane cost
        const float* wc = w + (ci * COUT + cog) * 9;
        const float* bc = bias + ci * COUT + cog;
#pragma unroll
        for (int co = 0; co < COG; ++co) {
            float s = 0.0f;                       // conv seeded from 0
#pragma unroll
            for (int k = 0; k < 9; ++k)
                s = fmaf(xv[k], wc[co * 9 + k], s);
            float y = s + bc[co];                 // bias: separate f32 add
            float q = rintf(y * QS);              // v_rndne_f32, half-even
            acc[co] = fmaf(q, DQ, acc[co]);       // dequant+sum (post-round)
        }
    }

    float* ob = out + ((size_t)b * COUT + cog) * H_ * W_;
    const int oh = tile_y + ty;
    const int ow = tile_x + tx;
#pragma unroll
    for (int co = 0; co < COG; ++co)
        ob[co * H_ * W_ + oh * W_ + ow] = acc[co];
}

extern "C" void kernel_launch(void* const* d_in, const int* in_sizes, int n_in,
                              void* d_out, int out_size, void* d_ws, size_t ws_size,
                              hipStream_t stream)
{
    const float* x    = (const float*)d_in[0];
    const float* w    = (const float*)d_in[1];
    const float* bias = (const float*)d_in[2];
    float* out        = (float*)d_out;

    dim3 grid(W_ / TILE, H_ / TILE, B_);   // (14, 14, 8) = 1568 blocks
    dim3 block(256);
    conv_quant_sum_kernel<<<grid, block, 0, stream>>>(x, w, bias, out);
}